// Round 8
// baseline (253.763 us; speedup 1.0000x reference)
//
#include <hip/hip_runtime.h>
#include <hip/hip_fp16.h>

#define WGS 256
#define HWGS 1024   // partition block size
#define TILE 8192   // edges per partition/hist block
#define BSH 7       // 128 nodes per bucket
#define CAP 2560    // per-bucket edge capacity: mean 2046, sd 45 -> 11 sigma slack

typedef _Float16 half8_t __attribute__((ext_vector_type(8)));
typedef _Float16 half4_t __attribute__((ext_vector_type(4)));
typedef float f32x4_t __attribute__((ext_vector_type(4)));

// ---------- dispatch 1: [partition counting-sort | W2-conv | degree hist] ----------
// Partition blocks (bx < PB): LDS hist -> scan -> reserve bucket chunks ->
//   bucket-ordered LDS scatter -> coalesced stream-out (round-6, validated).
//   pack = (local_col << 17) | row.
// bx == PB: W2 -> W2h (fp16, transposed, stride 72).
// bx > PB: global-atomic per-node degree histogram (round-5 validated this
//   fused-hist pattern as cheap; its failure was the scatter, not the hist).
// All three paths have disjoint outputs -> no intra-dispatch dependencies.
__global__ __launch_bounds__(HWGS) void k_partA(const int* __restrict__ row,
                                                const int* __restrict__ col,
                                                int* __restrict__ bcur,
                                                int* __restrict__ ebuf,
                                                const float* __restrict__ W2,
                                                _Float16* __restrict__ W2h,
                                                int* __restrict__ hist,
                                                int E, int nbk, int PB) {
  if (blockIdx.x == PB) {  // W2 -> W2h conversion
    for (int idx = threadIdx.x; idx < 64 * 64; idx += HWGS) {
      int c = idx & 63, k = idx >> 6;
      W2h[c * 72 + k] = (_Float16)W2[(k << 6) + c];
    }
    return;
  }
  if (blockIdx.x > PB) {  // degree histogram (fire-and-forget atomics)
    int hb = blockIdx.x - PB - 1;
    int base = hb * TILE, end = min(base + TILE, E);
    for (int e = base + threadIdx.x; e < end; e += HWGS)
      atomicAdd(&hist[col[e]], 1);
    return;
  }
  __shared__ int A[1024];              // hist -> local cursor
  __shared__ int B[1024];              // scan -> global offset delta
  __shared__ unsigned sbuf[TILE];      // bucket-ordered packed edges
  __shared__ unsigned short sbkt[TILE];
  const int tid = threadIdx.x;
  A[tid] = 0;
  __syncthreads();
  int base = blockIdx.x * TILE, end = min(base + TILE, E);
  int cnt = end - base;
  for (int e = base + tid; e < end; e += HWGS)
    atomicAdd(&A[col[e] >> BSH], 1);
  __syncthreads();
  // inclusive scan of A into B (Hillis-Steele, 1024 entries)
  B[tid] = A[tid];
  __syncthreads();
  for (int off = 1; off < 1024; off <<= 1) {
    int t = (tid >= off) ? B[tid - off] : 0;
    __syncthreads();
    B[tid] += t;
    __syncthreads();
  }
  {  // reserve global chunk; repurpose A -> local cursor, B -> gpos delta
    int h = A[tid];
    int start = B[tid] - h;             // exclusive local offset
    int cb = 0;
    if (tid < nbk && h) cb = atomicAdd(&bcur[tid], h);  // window-relative base
    A[tid] = start;
    B[tid] = tid * CAP + cb - start;    // gpos = idx + B[bk]
  }
  __syncthreads();
  for (int e = base + tid; e < end; e += HWGS) {
    int c = col[e], r = row[e];
    int bk = c >> BSH;
    int pos = atomicAdd(&A[bk], 1);     // pos < cnt always (sum of hist)
    sbuf[pos] = ((unsigned)(c & ((1 << BSH) - 1)) << 17) | (unsigned)r;
    sbkt[pos] = (unsigned short)bk;
  }
  __syncthreads();
  for (int idx = tid; idx < cnt; idx += HWGS) {
    int bk = sbkt[idx];
    int gpos = idx + B[bk];
    if (gpos < (bk + 1) * CAP) ebuf[gpos] = (int)sbuf[idx];  // overflow guard
  }
}

// ---------- dispatch 2: [gemm1 blocks | partB blocks] -- race-free ----------
// gemm1 (bx < GB): X[64,128] @ W1; epilogue derives dinv from hist (dispatch 1)
//   itself -- di = rsqrtf(hist[row]+1), writes dinv[row] and g = half(acc*di).
//   Bit-identical to round-6's k_gemm epilogue (same degree int, same rsqrtf,
//   same single fp16 round).
// partB (bx >= GB): reads hist (d1) for per-node counts (no ebuf hist pass),
//   scan -> range/cur, scatter csr from ebuf (d1).
// NO intra-dispatch data edges (round-7's tripwire race was partB reading
// same-dispatch gemm output; eliminated by the hist hoist).
__global__ __launch_bounds__(WGS) void k_mid(const float* __restrict__ x,
                                             const float* __restrict__ W1,
                                             const int* __restrict__ hist,
                                             const int* __restrict__ ebuf,
                                             const int* __restrict__ bcur,
                                             int2* __restrict__ range,
                                             float* __restrict__ dinv,
                                             int* __restrict__ csr,
                                             _Float16* __restrict__ g,
                                             int N, int GB) {
  __shared__ __align__(16) char smem[34816];
  const int bx = blockIdx.x;
  const int tid = threadIdx.x;

  if (bx < GB) {  // ---- gemm1: K=128, f32 input, fp16 dinv-scaled output ----
    _Float16* Xs = (_Float16*)smem;   // 64 x 136 halves
    _Float16* Wt = Xs + 64 * 136;     // 64 x 136 halves
    const int rb = bx * 64;
    for (int idx = tid; idx < 16 * 128; idx += WGS) {
      int elem = idx << 2;
      int r = elem >> 7, kk = elem & 127;
      int gr = rb + r;
      half4_t p = {};
      if (gr < N) {
        float4 xv = ((const float4*)(x + (long)gr * 128))[kk >> 2];
        p = half4_t{(_Float16)xv.x, (_Float16)xv.y, (_Float16)xv.z, (_Float16)xv.w};
      }
      *(half4_t*)&Xs[r * 136 + kk] = p;
    }
    for (int idx = tid; idx < 16 * 128; idx += WGS) {
      int c = idx & 63, k0 = (idx >> 6) << 2;
      half4_t p = half4_t{(_Float16)W1[(k0 + 0) * 64 + c], (_Float16)W1[(k0 + 1) * 64 + c],
                          (_Float16)W1[(k0 + 2) * 64 + c], (_Float16)W1[(k0 + 3) * 64 + c]};
      *(half4_t*)&Wt[c * 136 + k0] = p;
    }
    __syncthreads();
    const int w = tid >> 6, l = tid & 63;
    const int lm = l & 15, q = l >> 4;
    const _Float16* xb = &Xs[(w * 16 + lm) * 136 + q * 8];
    const _Float16* wb = &Wt[lm * 136 + q * 8];
    f32x4_t acc0 = {0.f, 0.f, 0.f, 0.f}, acc1 = acc0, acc2 = acc0, acc3 = acc0;
#pragma unroll
    for (int ks = 0; ks < 4; ++ks) {
      half8_t af = *(const half8_t*)(xb + ks * 32);
      half8_t b0 = *(const half8_t*)(wb + 0 * 16 * 136 + ks * 32);
      half8_t b1 = *(const half8_t*)(wb + 1 * 16 * 136 + ks * 32);
      half8_t b2 = *(const half8_t*)(wb + 2 * 16 * 136 + ks * 32);
      half8_t b3 = *(const half8_t*)(wb + 3 * 16 * 136 + ks * 32);
      acc0 = __builtin_amdgcn_mfma_f32_16x16x32_f16(af, b0, acc0, 0, 0, 0);
      acc1 = __builtin_amdgcn_mfma_f32_16x16x32_f16(af, b1, acc1, 0, 0, 0);
      acc2 = __builtin_amdgcn_mfma_f32_16x16x32_f16(af, b2, acc2, 0, 0, 0);
      acc3 = __builtin_amdgcn_mfma_f32_16x16x32_f16(af, b3, acc3, 0, 0, 0);
    }
    __syncthreads();  // done reading Xs/Wt; reuse Xs as fp16 epilogue buffer
    _Float16* Epi = (_Float16*)smem;  // stride 72
#pragma unroll
    for (int r = 0; r < 4; ++r) {
      int lrow = w * 16 + q * 4 + r;
      int grow = rb + lrow;
      float di = 0.f;
      if (grow < N) {
        di = rsqrtf((float)hist[grow] + 1.0f);  // +1 self loop
        if (lm == 0) dinv[grow] = di;           // one writer per row
      }
      Epi[lrow * 72 + lm +  0] = (_Float16)(acc0[r] * di);
      Epi[lrow * 72 + lm + 16] = (_Float16)(acc1[r] * di);
      Epi[lrow * 72 + lm + 32] = (_Float16)(acc2[r] * di);
      Epi[lrow * 72 + lm + 48] = (_Float16)(acc3[r] * di);
    }
    __syncthreads();
    for (int idx = tid; idx < 512; idx += WGS) {  // 64 rows x 8 uint4
      int r = idx >> 3, cg = idx & 7;
      int grow = rb + r;
      if (grow < N)
        *(uint4*)(g + (long)grow * 64 + cg * 8) = *(const uint4*)&Epi[r * 72 + cg * 8];
    }
    return;
  }

  // ---- partB: hist-driven scan -> range/cur, csr scatter from ebuf ----
  int b = bx - GB;
  int* loff = (int*)smem;              // [128]
  int* cur  = loff + (1 << BSH);       // [128]
  int nodeBase = b << BSH;
  int nodeCnt = min(1 << BSH, N - nodeBase);
  int h = 0;
  if (tid < nodeCnt) h = hist[nodeBase + tid];
  if (tid < (1 << BSH)) loff[tid] = h;
  __syncthreads();
  for (int off = 1; off < (1 << BSH); off <<= 1) {
    int t = 0;
    if (tid < (1 << BSH) && tid >= off) t = loff[tid - off];
    __syncthreads();
    if (tid < (1 << BSH)) loff[tid] += t;  // inclusive
    __syncthreads();
  }
  if (tid < nodeCnt) {
    int ex = b * CAP + loff[tid] - h;  // exclusive, bucket-local absolute
    range[nodeBase + tid] = make_int2(ex, ex + h);
    cur[tid] = ex;
  }
  __syncthreads();
  int cnt = min(bcur[b], CAP);
  int base = b * CAP;
  for (int j = tid; j < cnt; j += WGS) {
    int v = ebuf[base + j];
    int pos = atomicAdd(&cur[((unsigned)v) >> 17], 1);
    csr[pos] = v & 0x1FFFF;
  }
}

// ---------- pull aggregation: 8 lanes/node, 8 nodes/wave, 8-deep MLP ----------
#define ACC(raw)                            \
  {                                         \
    a0 = __hadd2(a0, *(__half2*)&(raw).x);  \
    a1 = __hadd2(a1, *(__half2*)&(raw).y);  \
    a2 = __hadd2(a2, *(__half2*)&(raw).z);  \
    a3 = __hadd2(a3, *(__half2*)&(raw).w);  \
  }

template <bool RELU, bool OUTH>
__global__ __launch_bounds__(WGS) void k_aggr(const int2* __restrict__ range,
                                              const int* __restrict__ csr,
                                              const _Float16* __restrict__ g,
                                              const float* __restrict__ dinv,
                                              const float* __restrict__ b,
                                              void* __restrict__ outv, int N) {
  int t = blockIdx.x * WGS + threadIdx.x;
  int node = t >> 3;
  if (node >= N) return;
  int c = threadIdx.x & 7;
  const uint4* gv = (const uint4*)g;
  __half2 a0, a1, a2, a3;
  {  // self loop initializes the accumulator
    uint4 r0 = gv[(long)node * 8 + c];
    a0 = *(__half2*)&r0.x; a1 = *(__half2*)&r0.y;
    a2 = *(__half2*)&r0.z; a3 = *(__half2*)&r0.w;
  }
  int2 rg = range[node];
  const int* cp = csr + rg.x;
  int deg = rg.y - rg.x;
  int i = 0;
  for (; i + 8 <= deg; i += 8) {
    int s0 = cp[i],     s1 = cp[i + 1], s2 = cp[i + 2], s3 = cp[i + 3];
    int s4 = cp[i + 4], s5 = cp[i + 5], s6 = cp[i + 6], s7 = cp[i + 7];
    uint4 r0 = gv[(long)s0 * 8 + c];
    uint4 r1 = gv[(long)s1 * 8 + c];
    uint4 r2 = gv[(long)s2 * 8 + c];
    uint4 r3 = gv[(long)s3 * 8 + c];
    uint4 r4 = gv[(long)s4 * 8 + c];
    uint4 r5 = gv[(long)s5 * 8 + c];
    uint4 r6 = gv[(long)s6 * 8 + c];
    uint4 r7 = gv[(long)s7 * 8 + c];
    ACC(r0); ACC(r1); ACC(r2); ACC(r3);
    ACC(r4); ACC(r5); ACC(r6); ACC(r7);
  }
  if (i + 4 <= deg) {
    int s0 = cp[i], s1 = cp[i + 1], s2 = cp[i + 2], s3 = cp[i + 3];
    uint4 r0 = gv[(long)s0 * 8 + c];
    uint4 r1 = gv[(long)s1 * 8 + c];
    uint4 r2 = gv[(long)s2 * 8 + c];
    uint4 r3 = gv[(long)s3 * 8 + c];
    ACC(r0); ACC(r1); ACC(r2); ACC(r3);
    i += 4;
  }
  for (; i < deg; ++i) {
    uint4 r0 = gv[(long)cp[i] * 8 + c];
    ACC(r0);
  }
  float di = dinv[node];
  float2 f0 = __half22float2(a0), f1 = __half22float2(a1);
  float2 f2 = __half22float2(a2), f3 = __half22float2(a3);
  float4 b0 = ((const float4*)b)[2 * c];
  float4 b1 = ((const float4*)b)[2 * c + 1];
  float o0 = fmaf(f0.x, di, b0.x), o1 = fmaf(f0.y, di, b0.y);
  float o2 = fmaf(f1.x, di, b0.z), o3 = fmaf(f1.y, di, b0.w);
  float o4 = fmaf(f2.x, di, b1.x), o5 = fmaf(f2.y, di, b1.y);
  float o6 = fmaf(f3.x, di, b1.z), o7 = fmaf(f3.y, di, b1.w);
  if (RELU) {
    o0 = fmaxf(o0, 0.f); o1 = fmaxf(o1, 0.f); o2 = fmaxf(o2, 0.f);
    o3 = fmaxf(o3, 0.f); o4 = fmaxf(o4, 0.f); o5 = fmaxf(o5, 0.f);
    o6 = fmaxf(o6, 0.f); o7 = fmaxf(o7, 0.f);
  }
  if (OUTH) {
    __half2 p0 = __floats2half2_rn(o0, o1);
    __half2 p1 = __floats2half2_rn(o2, o3);
    __half2 p2 = __floats2half2_rn(o4, o5);
    __half2 p3 = __floats2half2_rn(o6, o7);
    uint4 pk = make_uint4(*(unsigned*)&p0, *(unsigned*)&p1,
                          *(unsigned*)&p2, *(unsigned*)&p3);
    ((uint4*)outv)[(long)node * 8 + c] = pk;
  } else {
    float* orow = (float*)outv + (long)node * 64 + c * 8;
    *(float4*)orow = make_float4(o0, o1, o2, o3);
    *(float4*)(orow + 4) = make_float4(o4, o5, o6, o7);
  }
}

// ---------- fused layer-1 aggregation + layer-2 GEMM ----------
// REQUIRES N % 32 == 0 (true: 100000 = 3125*32) so no early-outs before barriers.
__global__ __launch_bounds__(WGS) void k_aggr1f(const int2* __restrict__ range,
                                                const int* __restrict__ csr,
                                                const _Float16* __restrict__ g,
                                                const float* __restrict__ dinv,
                                                const float* __restrict__ b,
                                                const _Float16* __restrict__ W2h,
                                                _Float16* __restrict__ g2, int N) {
  __shared__ __align__(16) _Float16 Hs[32 * 72];  // relu(h) tile / epilogue buffer
  const int tid = threadIdx.x;
  const int lnode = tid >> 3;                 // 0..31
  const int node = blockIdx.x * 32 + lnode;   // < N always (grid exact)
  const int c = tid & 7;
  const uint4* gv = (const uint4*)g;
  __half2 a0, a1, a2, a3;
  {  // self loop initializes the accumulator
    uint4 r0 = gv[(long)node * 8 + c];
    a0 = *(__half2*)&r0.x; a1 = *(__half2*)&r0.y;
    a2 = *(__half2*)&r0.z; a3 = *(__half2*)&r0.w;
  }
  int2 rg = range[node];
  const int* cp = csr + rg.x;
  int deg = rg.y - rg.x;
  int i = 0;
  for (; i + 8 <= deg; i += 8) {
    int s0 = cp[i],     s1 = cp[i + 1], s2 = cp[i + 2], s3 = cp[i + 3];
    int s4 = cp[i + 4], s5 = cp[i + 5], s6 = cp[i + 6], s7 = cp[i + 7];
    uint4 r0 = gv[(long)s0 * 8 + c];
    uint4 r1 = gv[(long)s1 * 8 + c];
    uint4 r2 = gv[(long)s2 * 8 + c];
    uint4 r3 = gv[(long)s3 * 8 + c];
    uint4 r4 = gv[(long)s4 * 8 + c];
    uint4 r5 = gv[(long)s5 * 8 + c];
    uint4 r6 = gv[(long)s6 * 8 + c];
    uint4 r7 = gv[(long)s7 * 8 + c];
    ACC(r0); ACC(r1); ACC(r2); ACC(r3);
    ACC(r4); ACC(r5); ACC(r6); ACC(r7);
  }
  if (i + 4 <= deg) {
    int s0 = cp[i], s1 = cp[i + 1], s2 = cp[i + 2], s3 = cp[i + 3];
    uint4 r0 = gv[(long)s0 * 8 + c];
    uint4 r1 = gv[(long)s1 * 8 + c];
    uint4 r2 = gv[(long)s2 * 8 + c];
    uint4 r3 = gv[(long)s3 * 8 + c];
    ACC(r0); ACC(r1); ACC(r2); ACC(r3);
    i += 4;
  }
  for (; i < deg; ++i) {
    uint4 r0 = gv[(long)cp[i] * 8 + c];
    ACC(r0);
  }
  float di = dinv[node];
  float2 f0 = __half22float2(a0), f1 = __half22float2(a1);
  float2 f2 = __half22float2(a2), f3 = __half22float2(a3);
  float4 b0 = ((const float4*)b)[2 * c];
  float4 b1 = ((const float4*)b)[2 * c + 1];
  float o0 = fmaf(f0.x, di, b0.x), o1 = fmaf(f0.y, di, b0.y);
  float o2 = fmaf(f1.x, di, b0.z), o3 = fmaf(f1.y, di, b0.w);
  float o4 = fmaf(f2.x, di, b1.x), o5 = fmaf(f2.y, di, b1.y);
  float o6 = fmaf(f3.x, di, b1.z), o7 = fmaf(f3.y, di, b1.w);
  o0 = fmaxf(o0, 0.f); o1 = fmaxf(o1, 0.f); o2 = fmaxf(o2, 0.f);
  o3 = fmaxf(o3, 0.f); o4 = fmaxf(o4, 0.f); o5 = fmaxf(o5, 0.f);
  o6 = fmaxf(o6, 0.f); o7 = fmaxf(o7, 0.f);
  {  // h tile (same __floats2half2_rn rounding) -> LDS, stride 72
    __half2 p0 = __floats2half2_rn(o0, o1);
    __half2 p1 = __floats2half2_rn(o2, o3);
    __half2 p2 = __floats2half2_rn(o4, o5);
    __half2 p3 = __floats2half2_rn(o6, o7);
    uint4 pk = make_uint4(*(unsigned*)&p0, *(unsigned*)&p1,
                          *(unsigned*)&p2, *(unsigned*)&p3);
    *(uint4*)&Hs[lnode * 72 + c * 8] = pk;
  }
  __syncthreads();
  // 32x64 = relu(H) @ W2: 4 waves; wave w -> m-tile (w&1), n-tiles {2*(w>>1), +1}
  const int w = tid >> 6, l = tid & 63;
  const int lm = l & 15, q = l >> 4;
  const int mt = w & 1, n0 = (w >> 1) << 1;
  const _Float16* ab = &Hs[(mt * 16 + lm) * 72 + q * 8];
  const _Float16* wb = W2h + (n0 * 16 + lm) * 72 + q * 8;  // B-frags from L2
  f32x4_t acc0 = {0.f, 0.f, 0.f, 0.f}, acc1 = acc0;
#pragma unroll
  for (int ks = 0; ks < 2; ++ks) {
    half8_t af = *(const half8_t*)(ab + ks * 32);
    half8_t w0 = *(const half8_t*)(wb + ks * 32);
    half8_t w1 = *(const half8_t*)(wb + 16 * 72 + ks * 32);
    acc0 = __builtin_amdgcn_mfma_f32_16x16x32_f16(af, w0, acc0, 0, 0, 0);
    acc1 = __builtin_amdgcn_mfma_f32_16x16x32_f16(af, w1, acc1, 0, 0, 0);
  }
  __syncthreads();  // all waves done reading Hs; reuse as epilogue buffer
#pragma unroll
  for (int r = 0; r < 4; ++r) {
    int lrow = mt * 16 + q * 4 + r;
    float d2 = dinv[blockIdx.x * 32 + lrow];
    Hs[lrow * 72 + n0 * 16 + lm]       = (_Float16)(acc0[r] * d2);
    Hs[lrow * 72 + (n0 + 1) * 16 + lm] = (_Float16)(acc1[r] * d2);
  }
  __syncthreads();
  {  // coalesced store: 32 rows x 8 uint4
    int rr = tid >> 3, cg = tid & 7;
    *(uint4*)(g2 + (long)(blockIdx.x * 32 + rr) * 64 + cg * 8) =
        *(const uint4*)&Hs[rr * 72 + cg * 8];
  }
}
#undef ACC

extern "C" void kernel_launch(void* const* d_in, const int* in_sizes, int n_in,
                              void* d_out, int out_size, void* d_ws, size_t ws_size,
                              hipStream_t stream) {
  const float* x  = (const float*)d_in[0];
  const int*   ei = (const int*)d_in[1];
  const float* W1 = (const float*)d_in[2];
  const float* b1 = (const float*)d_in[3];
  const float* W2 = (const float*)d_in[4];
  const float* b2 = (const float*)d_in[5];
  float* out = (float*)d_out;

  const int N = in_sizes[0] / 128;  // 100000
  const int E = in_sizes[1] / 2;    // 1600000
  const int* row = ei;              // sources
  const int* col = ei + E;          // targets

  const int nbk = (N + (1 << BSH) - 1) >> BSH;  // 782 buckets (<=1024)
  const int PB  = (E + TILE - 1) / TILE;        // partition blocks (196)
  const int HB  = (E + TILE - 1) / TILE;        // hist blocks (196)
  const int GB  = (N + 63) / 64;                // gemm1 blocks (1563)

  int Npad = (N + 3) & ~3;
  int*      hist  = (int*)d_ws;              // [Npad]  (zeroed)
  int*      bcur  = hist + Npad;             // [1024]  (zeroed)
  float*    dinv  = (float*)(bcur + 1024);   // [Npad]
  int2*     range = (int2*)(dinv + Npad);    // [N]
  int*      csr   = (int*)(range + N);       // [nbk*CAP]
  int*      ebuf  = csr + (size_t)nbk * CAP; // [nbk*CAP]
  _Float16* g     = (_Float16*)(ebuf + (size_t)nbk * CAP);  // [N*64] fp16 (scaled)
  _Float16* g2    = g + (size_t)N * 64;      // [N*64] fp16 (layer-2 pre-agg)
  _Float16* W2h   = g2 + (size_t)N * 64;     // [64*72] fp16 transposed W2

  // ---- dispatch 1: binning + W2-conv + degree hist (disjoint outputs) ----
  hipMemsetAsync(hist, 0, (size_t)(Npad + 1024) * sizeof(int), stream);
  k_partA<<<PB + 1 + HB, HWGS, 0, stream>>>(row, col, bcur, ebuf, W2, W2h,
                                            hist, E, nbk, PB);

  // ---- dispatch 2: [gemm1 (dinv from hist, fp16 out) | partB] -- no deps ----
  k_mid<<<GB + nbk, WGS, 0, stream>>>(x, W1, hist, ebuf, bcur, range, dinv,
                                      csr, g, N, GB);

  // ---- layer-1 aggregation fused with layer-2 GEMM ----
  k_aggr1f<<<(N + 31) / 32, WGS, 0, stream>>>(range, csr, g, dinv, b1, W2h, g2, N);

  // ---- layer-2 aggregation ----
  int aggGrid = (N * 8 + WGS - 1) / WGS;  // 8 lanes per node
  k_aggr<false, false><<<aggGrid, WGS, 0, stream>>>(range, csr, g2, dinv, b2, out, N);
}

// Round 9
// 209.914 us; speedup vs baseline: 1.2089x; 1.2089x over previous
//
#include <hip/hip_runtime.h>
#include <hip/hip_fp16.h>

#define WGS 256
#define HWGS 1024   // partition block size
#define TILE 8192   // edges per partition block
#define BSH 7       // 128 nodes per bucket
#define CAP 2560    // per-bucket edge capacity: mean 2046, sd 45 -> 11 sigma slack

typedef _Float16 half8_t __attribute__((ext_vector_type(8)));
typedef _Float16 half4_t __attribute__((ext_vector_type(4)));
typedef float f32x4_t __attribute__((ext_vector_type(4)));

// ---------- single-pass partition with LDS counting sort (round-6, best) ----------
// pack = (local_col << 17) | row   (row < 2^17, local_col < 128)
// Phases: LDS hist -> scan -> reserve bucket chunks -> bucket-ordered LDS
// scatter -> coalesced stream-out. Extra trailing block converts W2 -> W2h.
// CLOSED BRANCHES (refuted by measurement): fusing gemm into this grid
// (R2/R3: 62-71us), global-atomic degree hist (R8: 72us, 60MB write-amp),
// direct global CSR scatter (R5: 152us, 16x write-amp).
__global__ __launch_bounds__(HWGS) void k_partA(const int* __restrict__ row,
                                                const int* __restrict__ col,
                                                int* __restrict__ bcur,
                                                int* __restrict__ ebuf,
                                                const float* __restrict__ W2,
                                                _Float16* __restrict__ W2h,
                                                int E, int nbk, int PB) {
  if (blockIdx.x >= PB) {  // W2 -> W2h conversion (off critical path)
    for (int idx = threadIdx.x; idx < 64 * 64; idx += HWGS) {
      int c = idx & 63, k = idx >> 6;
      W2h[c * 72 + k] = (_Float16)W2[(k << 6) + c];
    }
    return;
  }
  __shared__ int A[1024];              // hist -> local cursor
  __shared__ int B[1024];              // scan -> global offset delta
  __shared__ unsigned sbuf[TILE];      // bucket-ordered packed edges
  __shared__ unsigned short sbkt[TILE];
  const int tid = threadIdx.x;
  A[tid] = 0;
  __syncthreads();
  int base = blockIdx.x * TILE, end = min(base + TILE, E);
  int cnt = end - base;
  for (int e = base + tid; e < end; e += HWGS)
    atomicAdd(&A[col[e] >> BSH], 1);
  __syncthreads();
  // inclusive scan of A into B (Hillis-Steele, 1024 entries)
  B[tid] = A[tid];
  __syncthreads();
  for (int off = 1; off < 1024; off <<= 1) {
    int t = (tid >= off) ? B[tid - off] : 0;
    __syncthreads();
    B[tid] += t;
    __syncthreads();
  }
  {  // reserve global chunk; repurpose A -> local cursor, B -> gpos delta
    int h = A[tid];
    int start = B[tid] - h;             // exclusive local offset
    int cb = 0;
    if (tid < nbk && h) cb = atomicAdd(&bcur[tid], h);  // window-relative base
    A[tid] = start;
    B[tid] = tid * CAP + cb - start;    // gpos = idx + B[bk]
  }
  __syncthreads();
  for (int e = base + tid; e < end; e += HWGS) {
    int c = col[e], r = row[e];
    int bk = c >> BSH;
    int pos = atomicAdd(&A[bk], 1);     // pos < cnt always (sum of hist)
    sbuf[pos] = ((unsigned)(c & ((1 << BSH) - 1)) << 17) | (unsigned)r;
    sbkt[pos] = (unsigned short)bk;
  }
  __syncthreads();
  for (int idx = tid; idx < cnt; idx += HWGS) {
    int bk = sbkt[idx];
    int gpos = idx + B[bk];
    if (gpos < (bk + 1) * CAP) ebuf[gpos] = (int)sbuf[idx];  // overflow guard
  }
}

// ---------- partition pass B: one block per bucket ----------
// NEW vs round-6: the bucket's ebuf window (<=10KB) is staged into LDS once
// (coalesced), and both the node-hist and the csr scatter read from LDS --
// halves partB's global read traffic, removes the second dependent pass.
__global__ __launch_bounds__(WGS) void k_partB(const int* __restrict__ ebuf,
                                               const int* __restrict__ bcur,
                                               int2* __restrict__ range,
                                               float* __restrict__ dinv,
                                               int* __restrict__ csr, int N) {
  int b = blockIdx.x;
  int nodeBase = b << BSH;
  int nodeCnt = min(1 << BSH, N - nodeBase);
  __shared__ int hcnt[1 << BSH];
  __shared__ int loff[1 << BSH];
  __shared__ int cur[1 << BSH];
  __shared__ int se[CAP];              // staged bucket window (10240 B)
  for (int i = threadIdx.x; i < (1 << BSH); i += WGS) hcnt[i] = 0;
  int cnt = min(bcur[b], CAP);
  int base = b * CAP;
  for (int j = threadIdx.x; j < cnt; j += WGS) se[j] = ebuf[base + j];
  __syncthreads();
  for (int j = threadIdx.x; j < cnt; j += WGS)
    atomicAdd(&hcnt[((unsigned)se[j]) >> 17], 1);
  __syncthreads();
  if (threadIdx.x < (1 << BSH)) loff[threadIdx.x] = hcnt[threadIdx.x];
  __syncthreads();
  for (int off = 1; off < (1 << BSH); off <<= 1) {
    int t = 0;
    if (threadIdx.x < (1 << BSH) && threadIdx.x >= off) t = loff[threadIdx.x - off];
    __syncthreads();
    if (threadIdx.x < (1 << BSH)) loff[threadIdx.x] += t;  // inclusive
    __syncthreads();
  }
  for (int i = threadIdx.x; i < nodeCnt; i += WGS) {
    int ex = base + loff[i] - hcnt[i];  // exclusive, bucket-local absolute
    range[nodeBase + i] = make_int2(ex, ex + hcnt[i]);
    cur[i] = ex;
    dinv[nodeBase + i] = rsqrtf((float)hcnt[i] + 1.0f);  // +1 self loop
  }
  __syncthreads();
  for (int j = threadIdx.x; j < cnt; j += WGS) {
    int v = se[j];
    int pos = atomicAdd(&cur[((unsigned)v) >> 17], 1);
    csr[pos] = v & 0x1FFFF;
  }
}

// ---------- MFMA fp16 GEMM: Y[n,64] = half( (X[n,K] @ W[K,64]) * dinv[n] ) ----------
template <int K, bool HIN>
__global__ __launch_bounds__(WGS) void k_gemm(const void* __restrict__ Xv,
                                              const float* __restrict__ W,
                                              const float* __restrict__ dinv,
                                              _Float16* __restrict__ Y, int n) {
  constexpr int SX = K + 8;
  constexpr int LOGK = (K == 128) ? 7 : 6;
  __shared__ _Float16 Xs[64 * SX];   // also reused as 64x72 epilogue buffer
  __shared__ _Float16 Wt[64 * SX];
  const int tid = threadIdx.x;
  const int rb = blockIdx.x * 64;
  for (int idx = tid; idx < 16 * K; idx += WGS) {
    int elem = idx << 2;
    int r = elem >> LOGK, kk = elem & (K - 1);
    int gr = rb + r;
    half4_t p = {};
    if (gr < n) {
      if (HIN) {
        p = *(const half4_t*)((const _Float16*)Xv + (long)gr * K + kk);
      } else {
        float4 xv = ((const float4*)((const float*)Xv + (long)gr * K))[kk >> 2];
        p = half4_t{(_Float16)xv.x, (_Float16)xv.y, (_Float16)xv.z, (_Float16)xv.w};
      }
    }
    *(half4_t*)&Xs[r * SX + kk] = p;
  }
  for (int idx = tid; idx < 16 * K; idx += WGS) {
    int c = idx & 63, k0 = (idx >> 6) << 2;
    half4_t p = half4_t{(_Float16)W[(k0 + 0) * 64 + c], (_Float16)W[(k0 + 1) * 64 + c],
                        (_Float16)W[(k0 + 2) * 64 + c], (_Float16)W[(k0 + 3) * 64 + c]};
    *(half4_t*)&Wt[c * SX + k0] = p;
  }
  __syncthreads();
  const int w = tid >> 6, l = tid & 63;
  const int lm = l & 15, q = l >> 4;
  const _Float16* xb = &Xs[(w * 16 + lm) * SX + q * 8];
  const _Float16* wb = &Wt[lm * SX + q * 8];
  f32x4_t acc0 = {0.f, 0.f, 0.f, 0.f}, acc1 = acc0, acc2 = acc0, acc3 = acc0;
#pragma unroll
  for (int ks = 0; ks < K / 32; ++ks) {
    half8_t af = *(const half8_t*)(xb + ks * 32);
    half8_t b0 = *(const half8_t*)(wb + 0 * 16 * SX + ks * 32);
    half8_t b1 = *(const half8_t*)(wb + 1 * 16 * SX + ks * 32);
    half8_t b2 = *(const half8_t*)(wb + 2 * 16 * SX + ks * 32);
    half8_t b3 = *(const half8_t*)(wb + 3 * 16 * SX + ks * 32);
    acc0 = __builtin_amdgcn_mfma_f32_16x16x32_f16(af, b0, acc0, 0, 0, 0);
    acc1 = __builtin_amdgcn_mfma_f32_16x16x32_f16(af, b1, acc1, 0, 0, 0);
    acc2 = __builtin_amdgcn_mfma_f32_16x16x32_f16(af, b2, acc2, 0, 0, 0);
    acc3 = __builtin_amdgcn_mfma_f32_16x16x32_f16(af, b3, acc3, 0, 0, 0);
  }
  __syncthreads();  // done reading Xs/Wt; reuse Xs as epilogue buffer
  _Float16* Epi = Xs;  // stride 72
#pragma unroll
  for (int r = 0; r < 4; ++r) {
    int lrow = w * 16 + q * 4 + r;
    int grow = rb + lrow;
    float di = (grow < n) ? dinv[grow] : 0.f;
    Epi[lrow * 72 + lm +  0] = (_Float16)(acc0[r] * di);
    Epi[lrow * 72 + lm + 16] = (_Float16)(acc1[r] * di);
    Epi[lrow * 72 + lm + 32] = (_Float16)(acc2[r] * di);
    Epi[lrow * 72 + lm + 48] = (_Float16)(acc3[r] * di);
  }
  __syncthreads();
  for (int idx = tid; idx < 512; idx += WGS) {  // 64 rows x 8 uint4
    int r = idx >> 3, cg = idx & 7;
    int grow = rb + r;
    if (grow < n)
      *(uint4*)(Y + (long)grow * 64 + cg * 8) = *(const uint4*)&Epi[r * 72 + cg * 8];
  }
}

// ---------- pull aggregation: 8 lanes/node, 8 nodes/wave, 8-deep MLP ----------
#define ACC(raw)                            \
  {                                         \
    a0 = __hadd2(a0, *(__half2*)&(raw).x);  \
    a1 = __hadd2(a1, *(__half2*)&(raw).y);  \
    a2 = __hadd2(a2, *(__half2*)&(raw).z);  \
    a3 = __hadd2(a3, *(__half2*)&(raw).w);  \
  }

template <bool RELU, bool OUTH>
__global__ __launch_bounds__(WGS) void k_aggr(const int2* __restrict__ range,
                                              const int* __restrict__ csr,
                                              const _Float16* __restrict__ g,
                                              const float* __restrict__ dinv,
                                              const float* __restrict__ b,
                                              void* __restrict__ outv, int N) {
  int t = blockIdx.x * WGS + threadIdx.x;
  int node = t >> 3;
  if (node >= N) return;
  int c = threadIdx.x & 7;
  const uint4* gv = (const uint4*)g;
  __half2 a0, a1, a2, a3;
  {  // self loop initializes the accumulator
    uint4 r0 = gv[(long)node * 8 + c];
    a0 = *(__half2*)&r0.x; a1 = *(__half2*)&r0.y;
    a2 = *(__half2*)&r0.z; a3 = *(__half2*)&r0.w;
  }
  int2 rg = range[node];
  const int* cp = csr + rg.x;
  int deg = rg.y - rg.x;
  int i = 0;
  for (; i + 8 <= deg; i += 8) {
    int s0 = cp[i],     s1 = cp[i + 1], s2 = cp[i + 2], s3 = cp[i + 3];
    int s4 = cp[i + 4], s5 = cp[i + 5], s6 = cp[i + 6], s7 = cp[i + 7];
    uint4 r0 = gv[(long)s0 * 8 + c];
    uint4 r1 = gv[(long)s1 * 8 + c];
    uint4 r2 = gv[(long)s2 * 8 + c];
    uint4 r3 = gv[(long)s3 * 8 + c];
    uint4 r4 = gv[(long)s4 * 8 + c];
    uint4 r5 = gv[(long)s5 * 8 + c];
    uint4 r6 = gv[(long)s6 * 8 + c];
    uint4 r7 = gv[(long)s7 * 8 + c];
    ACC(r0); ACC(r1); ACC(r2); ACC(r3);
    ACC(r4); ACC(r5); ACC(r6); ACC(r7);
  }
  if (i + 4 <= deg) {
    int s0 = cp[i], s1 = cp[i + 1], s2 = cp[i + 2], s3 = cp[i + 3];
    uint4 r0 = gv[(long)s0 * 8 + c];
    uint4 r1 = gv[(long)s1 * 8 + c];
    uint4 r2 = gv[(long)s2 * 8 + c];
    uint4 r3 = gv[(long)s3 * 8 + c];
    ACC(r0); ACC(r1); ACC(r2); ACC(r3);
    i += 4;
  }
  for (; i < deg; ++i) {
    uint4 r0 = gv[(long)cp[i] * 8 + c];
    ACC(r0);
  }
  float di = dinv[node];
  float2 f0 = __half22float2(a0), f1 = __half22float2(a1);
  float2 f2 = __half22float2(a2), f3 = __half22float2(a3);
  float4 b0 = ((const float4*)b)[2 * c];
  float4 b1 = ((const float4*)b)[2 * c + 1];
  float o0 = fmaf(f0.x, di, b0.x), o1 = fmaf(f0.y, di, b0.y);
  float o2 = fmaf(f1.x, di, b0.z), o3 = fmaf(f1.y, di, b0.w);
  float o4 = fmaf(f2.x, di, b1.x), o5 = fmaf(f2.y, di, b1.y);
  float o6 = fmaf(f3.x, di, b1.z), o7 = fmaf(f3.y, di, b1.w);
  if (RELU) {
    o0 = fmaxf(o0, 0.f); o1 = fmaxf(o1, 0.f); o2 = fmaxf(o2, 0.f);
    o3 = fmaxf(o3, 0.f); o4 = fmaxf(o4, 0.f); o5 = fmaxf(o5, 0.f);
    o6 = fmaxf(o6, 0.f); o7 = fmaxf(o7, 0.f);
  }
  if (OUTH) {
    __half2 p0 = __floats2half2_rn(o0, o1);
    __half2 p1 = __floats2half2_rn(o2, o3);
    __half2 p2 = __floats2half2_rn(o4, o5);
    __half2 p3 = __floats2half2_rn(o6, o7);
    uint4 pk = make_uint4(*(unsigned*)&p0, *(unsigned*)&p1,
                          *(unsigned*)&p2, *(unsigned*)&p3);
    ((uint4*)outv)[(long)node * 8 + c] = pk;
  } else {
    float* orow = (float*)outv + (long)node * 64 + c * 8;
    *(float4*)orow = make_float4(o0, o1, o2, o3);
    *(float4*)(orow + 4) = make_float4(o4, o5, o6, o7);
  }
}

// ---------- fused layer-1 aggregation + layer-2 GEMM ----------
// REQUIRES N % 32 == 0 (true: 100000 = 3125*32) so no early-outs before barriers.
__global__ __launch_bounds__(WGS) void k_aggr1f(const int2* __restrict__ range,
                                                const int* __restrict__ csr,
                                                const _Float16* __restrict__ g,
                                                const float* __restrict__ dinv,
                                                const float* __restrict__ b,
                                                const _Float16* __restrict__ W2h,
                                                _Float16* __restrict__ g2, int N) {
  __shared__ __align__(16) _Float16 Hs[32 * 72];  // relu(h) tile / epilogue buffer
  const int tid = threadIdx.x;
  const int lnode = tid >> 3;                 // 0..31
  const int node = blockIdx.x * 32 + lnode;   // < N always (grid exact)
  const int c = tid & 7;
  const uint4* gv = (const uint4*)g;
  __half2 a0, a1, a2, a3;
  {  // self loop initializes the accumulator
    uint4 r0 = gv[(long)node * 8 + c];
    a0 = *(__half2*)&r0.x; a1 = *(__half2*)&r0.y;
    a2 = *(__half2*)&r0.z; a3 = *(__half2*)&r0.w;
  }
  int2 rg = range[node];
  const int* cp = csr + rg.x;
  int deg = rg.y - rg.x;
  int i = 0;
  for (; i + 8 <= deg; i += 8) {
    int s0 = cp[i],     s1 = cp[i + 1], s2 = cp[i + 2], s3 = cp[i + 3];
    int s4 = cp[i + 4], s5 = cp[i + 5], s6 = cp[i + 6], s7 = cp[i + 7];
    uint4 r0 = gv[(long)s0 * 8 + c];
    uint4 r1 = gv[(long)s1 * 8 + c];
    uint4 r2 = gv[(long)s2 * 8 + c];
    uint4 r3 = gv[(long)s3 * 8 + c];
    uint4 r4 = gv[(long)s4 * 8 + c];
    uint4 r5 = gv[(long)s5 * 8 + c];
    uint4 r6 = gv[(long)s6 * 8 + c];
    uint4 r7 = gv[(long)s7 * 8 + c];
    ACC(r0); ACC(r1); ACC(r2); ACC(r3);
    ACC(r4); ACC(r5); ACC(r6); ACC(r7);
  }
  if (i + 4 <= deg) {
    int s0 = cp[i], s1 = cp[i + 1], s2 = cp[i + 2], s3 = cp[i + 3];
    uint4 r0 = gv[(long)s0 * 8 + c];
    uint4 r1 = gv[(long)s1 * 8 + c];
    uint4 r2 = gv[(long)s2 * 8 + c];
    uint4 r3 = gv[(long)s3 * 8 + c];
    ACC(r0); ACC(r1); ACC(r2); ACC(r3);
    i += 4;
  }
  for (; i < deg; ++i) {
    uint4 r0 = gv[(long)cp[i] * 8 + c];
    ACC(r0);
  }
  float di = dinv[node];
  float2 f0 = __half22float2(a0), f1 = __half22float2(a1);
  float2 f2 = __half22float2(a2), f3 = __half22float2(a3);
  float4 b0 = ((const float4*)b)[2 * c];
  float4 b1 = ((const float4*)b)[2 * c + 1];
  float o0 = fmaf(f0.x, di, b0.x), o1 = fmaf(f0.y, di, b0.y);
  float o2 = fmaf(f1.x, di, b0.z), o3 = fmaf(f1.y, di, b0.w);
  float o4 = fmaf(f2.x, di, b1.x), o5 = fmaf(f2.y, di, b1.y);
  float o6 = fmaf(f3.x, di, b1.z), o7 = fmaf(f3.y, di, b1.w);
  o0 = fmaxf(o0, 0.f); o1 = fmaxf(o1, 0.f); o2 = fmaxf(o2, 0.f);
  o3 = fmaxf(o3, 0.f); o4 = fmaxf(o4, 0.f); o5 = fmaxf(o5, 0.f);
  o6 = fmaxf(o6, 0.f); o7 = fmaxf(o7, 0.f);
  {  // h tile (same __floats2half2_rn rounding) -> LDS, stride 72
    __half2 p0 = __floats2half2_rn(o0, o1);
    __half2 p1 = __floats2half2_rn(o2, o3);
    __half2 p2 = __floats2half2_rn(o4, o5);
    __half2 p3 = __floats2half2_rn(o6, o7);
    uint4 pk = make_uint4(*(unsigned*)&p0, *(unsigned*)&p1,
                          *(unsigned*)&p2, *(unsigned*)&p3);
    *(uint4*)&Hs[lnode * 72 + c * 8] = pk;
  }
  __syncthreads();
  // 32x64 = relu(H) @ W2: 4 waves; wave w -> m-tile (w&1), n-tiles {2*(w>>1), +1}
  const int w = tid >> 6, l = tid & 63;
  const int lm = l & 15, q = l >> 4;
  const int mt = w & 1, n0 = (w >> 1) << 1;
  const _Float16* ab = &Hs[(mt * 16 + lm) * 72 + q * 8];
  const _Float16* wb = W2h + (n0 * 16 + lm) * 72 + q * 8;  // B-frags from L2
  f32x4_t acc0 = {0.f, 0.f, 0.f, 0.f}, acc1 = acc0;
#pragma unroll
  for (int ks = 0; ks < 2; ++ks) {
    half8_t af = *(const half8_t*)(ab + ks * 32);
    half8_t w0 = *(const half8_t*)(wb + ks * 32);
    half8_t w1 = *(const half8_t*)(wb + 16 * 72 + ks * 32);
    acc0 = __builtin_amdgcn_mfma_f32_16x16x32_f16(af, w0, acc0, 0, 0, 0);
    acc1 = __builtin_amdgcn_mfma_f32_16x16x32_f16(af, w1, acc1, 0, 0, 0);
  }
  __syncthreads();  // all waves done reading Hs; reuse as epilogue buffer
#pragma unroll
  for (int r = 0; r < 4; ++r) {
    int lrow = mt * 16 + q * 4 + r;
    float d2 = dinv[blockIdx.x * 32 + lrow];
    Hs[lrow * 72 + n0 * 16 + lm]       = (_Float16)(acc0[r] * d2);
    Hs[lrow * 72 + (n0 + 1) * 16 + lm] = (_Float16)(acc1[r] * d2);
  }
  __syncthreads();
  {  // coalesced store: 32 rows x 8 uint4
    int rr = tid >> 3, cg = tid & 7;
    *(uint4*)(g2 + (long)(blockIdx.x * 32 + rr) * 64 + cg * 8) =
        *(const uint4*)&Hs[rr * 72 + cg * 8];
  }
}
#undef ACC

extern "C" void kernel_launch(void* const* d_in, const int* in_sizes, int n_in,
                              void* d_out, int out_size, void* d_ws, size_t ws_size,
                              hipStream_t stream) {
  const float* x  = (const float*)d_in[0];
  const int*   ei = (const int*)d_in[1];
  const float* W1 = (const float*)d_in[2];
  const float* b1 = (const float*)d_in[3];
  const float* W2 = (const float*)d_in[4];
  const float* b2 = (const float*)d_in[5];
  float* out = (float*)d_out;

  const int N = in_sizes[0] / 128;  // 100000
  const int E = in_sizes[1] / 2;    // 1600000
  const int* row = ei;              // sources
  const int* col = ei + E;          // targets

  const int nbk = (N + (1 << BSH) - 1) >> BSH;  // 782 buckets (<=1024)
  const int PB  = (E + TILE - 1) / TILE;        // partition blocks (196)

  int Npad = (N + 3) & ~3;
  int*      bcur  = (int*)d_ws;              // [1024]  (zeroed)
  float*    dinv  = (float*)(bcur + 1024);   // [Npad]
  int2*     range = (int2*)(dinv + Npad);    // [N]
  int*      csr   = (int*)(range + N);       // [nbk*CAP]
  int*      ebuf  = csr + (size_t)nbk * CAP; // [nbk*CAP]
  _Float16* g     = (_Float16*)(ebuf + (size_t)nbk * CAP);  // [N*64] fp16
  _Float16* g2    = g + (size_t)N * 64;      // [N*64] fp16 (layer-2 pre-agg)
  _Float16* W2h   = g2 + (size_t)N * 64;     // [64*72] fp16 transposed W2

  // ---- CSR build + normalization (LDS counting sort); +1 block converts W2 ----
  hipMemsetAsync(bcur, 0, 1024 * sizeof(int), stream);
  k_partA<<<PB + 1, HWGS, 0, stream>>>(row, col, bcur, ebuf, W2, W2h, E, nbk, PB);
  k_partB<<<nbk, WGS, 0, stream>>>(ebuf, bcur, range, dinv, csr, N);

  // ---- layer 1 GEMM ----
  k_gemm<128, false><<<(N + 63) / 64, WGS, 0, stream>>>(x, W1, dinv, g, N);

  // ---- layer-1 aggregation fused with layer-2 GEMM ----
  k_aggr1f<<<(N + 31) / 32, WGS, 0, stream>>>(range, csr, g, dinv, b1, W2h, g2, N);

  // ---- layer-2 aggregation ----
  int aggGrid = (N * 8 + WGS - 1) / WGS;  // 8 lanes per node
  k_aggr<false, false><<<aggGrid, WGS, 0, stream>>>(range, csr, g2, dinv, b2, out, N);
}

// Round 10
// 204.010 us; speedup vs baseline: 1.2439x; 1.0289x over previous
//
#include <hip/hip_runtime.h>
#include <hip/hip_fp16.h>

#define WGS 256
#define HWGS 1024   // partition block size
#define TILE 8192   // edges per partition block
#define BSH 7       // 128 nodes per bucket
#define CAP 2560    // per-bucket edge capacity: mean 2046, sd 45 -> 11 sigma slack

typedef _Float16 half8_t __attribute__((ext_vector_type(8)));
typedef _Float16 half4_t __attribute__((ext_vector_type(4)));
typedef float f32x4_t __attribute__((ext_vector_type(4)));

// ---------- single-pass partition with LDS counting sort (round-6, best) ----------
// pack = (local_col << 17) | row   (row < 2^17, local_col < 128)
// Phases: LDS hist -> scan -> reserve bucket chunks -> bucket-ordered LDS
// scatter -> coalesced stream-out. Extra trailing block converts W2 -> W2h.
// CLOSED BRANCHES (refuted by measurement): fusing gemm into this grid
// (R2/R3: 62-71us), global-atomic degree hist (R8: 72us, 60MB write-amp),
// direct global CSR scatter (R5: 152us, 16x write-amp), partB LDS staging
// (R9: +3us, occupancy loss > L2-reread savings).
__global__ __launch_bounds__(HWGS) void k_partA(const int* __restrict__ row,
                                                const int* __restrict__ col,
                                                int* __restrict__ bcur,
                                                int* __restrict__ ebuf,
                                                const float* __restrict__ W2,
                                                _Float16* __restrict__ W2h,
                                                int E, int nbk, int PB) {
  if (blockIdx.x >= PB) {  // W2 -> W2h conversion (off critical path)
    for (int idx = threadIdx.x; idx < 64 * 64; idx += HWGS) {
      int c = idx & 63, k = idx >> 6;
      W2h[c * 72 + k] = (_Float16)W2[(k << 6) + c];
    }
    return;
  }
  __shared__ int A[1024];              // hist -> local cursor
  __shared__ int B[1024];              // scan -> global offset delta
  __shared__ unsigned sbuf[TILE];      // bucket-ordered packed edges
  __shared__ unsigned short sbkt[TILE];
  const int tid = threadIdx.x;
  A[tid] = 0;
  __syncthreads();
  int base = blockIdx.x * TILE, end = min(base + TILE, E);
  int cnt = end - base;
  for (int e = base + tid; e < end; e += HWGS)
    atomicAdd(&A[col[e] >> BSH], 1);
  __syncthreads();
  // inclusive scan of A into B (Hillis-Steele, 1024 entries)
  B[tid] = A[tid];
  __syncthreads();
  for (int off = 1; off < 1024; off <<= 1) {
    int t = (tid >= off) ? B[tid - off] : 0;
    __syncthreads();
    B[tid] += t;
    __syncthreads();
  }
  {  // reserve global chunk; repurpose A -> local cursor, B -> gpos delta
    int h = A[tid];
    int start = B[tid] - h;             // exclusive local offset
    int cb = 0;
    if (tid < nbk && h) cb = atomicAdd(&bcur[tid], h);  // window-relative base
    A[tid] = start;
    B[tid] = tid * CAP + cb - start;    // gpos = idx + B[bk]
  }
  __syncthreads();
  for (int e = base + tid; e < end; e += HWGS) {
    int c = col[e], r = row[e];
    int bk = c >> BSH;
    int pos = atomicAdd(&A[bk], 1);     // pos < cnt always (sum of hist)
    sbuf[pos] = ((unsigned)(c & ((1 << BSH) - 1)) << 17) | (unsigned)r;
    sbkt[pos] = (unsigned short)bk;
  }
  __syncthreads();
  for (int idx = tid; idx < cnt; idx += HWGS) {
    int bk = sbkt[idx];
    int gpos = idx + B[bk];
    if (gpos < (bk + 1) * CAP) ebuf[gpos] = (int)sbuf[idx];  // overflow guard
  }
}

// ---------- partition pass B: one block per bucket (round-6 two-pass form) ----------
__global__ __launch_bounds__(WGS) void k_partB(const int* __restrict__ ebuf,
                                               const int* __restrict__ bcur,
                                               int2* __restrict__ range,
                                               float* __restrict__ dinv,
                                               int* __restrict__ csr, int N) {
  int b = blockIdx.x;
  int nodeBase = b << BSH;
  int nodeCnt = min(1 << BSH, N - nodeBase);
  __shared__ int hcnt[1 << BSH];
  __shared__ int loff[1 << BSH];
  __shared__ int cur[1 << BSH];
  for (int i = threadIdx.x; i < (1 << BSH); i += WGS) hcnt[i] = 0;
  __syncthreads();
  int cnt = min(bcur[b], CAP);
  int base = b * CAP;
  for (int j = threadIdx.x; j < cnt; j += WGS)
    atomicAdd(&hcnt[((unsigned)ebuf[base + j]) >> 17], 1);
  __syncthreads();
  if (threadIdx.x < (1 << BSH)) loff[threadIdx.x] = hcnt[threadIdx.x];
  __syncthreads();
  for (int off = 1; off < (1 << BSH); off <<= 1) {
    int t = 0;
    if (threadIdx.x < (1 << BSH) && threadIdx.x >= off) t = loff[threadIdx.x - off];
    __syncthreads();
    if (threadIdx.x < (1 << BSH)) loff[threadIdx.x] += t;  // inclusive
    __syncthreads();
  }
  for (int i = threadIdx.x; i < nodeCnt; i += WGS) {
    int ex = base + loff[i] - hcnt[i];  // exclusive, bucket-local absolute
    range[nodeBase + i] = make_int2(ex, ex + hcnt[i]);
    cur[i] = ex;
    dinv[nodeBase + i] = rsqrtf((float)hcnt[i] + 1.0f);  // +1 self loop
  }
  __syncthreads();
  for (int j = threadIdx.x; j < cnt; j += WGS) {
    int v = ebuf[base + j];
    int pos = atomicAdd(&cur[((unsigned)v) >> 17], 1);
    csr[pos] = v & 0x1FFFF;
  }
}

// ---------- MFMA fp16 GEMM: Y[n,64] = half( (X[n,K] @ W[K,64]) * dinv[n] ) ----------
template <int K, bool HIN>
__global__ __launch_bounds__(WGS) void k_gemm(const void* __restrict__ Xv,
                                              const float* __restrict__ W,
                                              const float* __restrict__ dinv,
                                              _Float16* __restrict__ Y, int n) {
  constexpr int SX = K + 8;
  constexpr int LOGK = (K == 128) ? 7 : 6;
  __shared__ _Float16 Xs[64 * SX];   // also reused as 64x72 epilogue buffer
  __shared__ _Float16 Wt[64 * SX];
  const int tid = threadIdx.x;
  const int rb = blockIdx.x * 64;
  for (int idx = tid; idx < 16 * K; idx += WGS) {
    int elem = idx << 2;
    int r = elem >> LOGK, kk = elem & (K - 1);
    int gr = rb + r;
    half4_t p = {};
    if (gr < n) {
      if (HIN) {
        p = *(const half4_t*)((const _Float16*)Xv + (long)gr * K + kk);
      } else {
        float4 xv = ((const float4*)((const float*)Xv + (long)gr * K))[kk >> 2];
        p = half4_t{(_Float16)xv.x, (_Float16)xv.y, (_Float16)xv.z, (_Float16)xv.w};
      }
    }
    *(half4_t*)&Xs[r * SX + kk] = p;
  }
  for (int idx = tid; idx < 16 * K; idx += WGS) {
    int c = idx & 63, k0 = (idx >> 6) << 2;
    half4_t p = half4_t{(_Float16)W[(k0 + 0) * 64 + c], (_Float16)W[(k0 + 1) * 64 + c],
                        (_Float16)W[(k0 + 2) * 64 + c], (_Float16)W[(k0 + 3) * 64 + c]};
    *(half4_t*)&Wt[c * SX + k0] = p;
  }
  __syncthreads();
  const int w = tid >> 6, l = tid & 63;
  const int lm = l & 15, q = l >> 4;
  const _Float16* xb = &Xs[(w * 16 + lm) * SX + q * 8];
  const _Float16* wb = &Wt[lm * SX + q * 8];
  f32x4_t acc0 = {0.f, 0.f, 0.f, 0.f}, acc1 = acc0, acc2 = acc0, acc3 = acc0;
#pragma unroll
  for (int ks = 0; ks < K / 32; ++ks) {
    half8_t af = *(const half8_t*)(xb + ks * 32);
    half8_t b0 = *(const half8_t*)(wb + 0 * 16 * SX + ks * 32);
    half8_t b1 = *(const half8_t*)(wb + 1 * 16 * SX + ks * 32);
    half8_t b2 = *(const half8_t*)(wb + 2 * 16 * SX + ks * 32);
    half8_t b3 = *(const half8_t*)(wb + 3 * 16 * SX + ks * 32);
    acc0 = __builtin_amdgcn_mfma_f32_16x16x32_f16(af, b0, acc0, 0, 0, 0);
    acc1 = __builtin_amdgcn_mfma_f32_16x16x32_f16(af, b1, acc1, 0, 0, 0);
    acc2 = __builtin_amdgcn_mfma_f32_16x16x32_f16(af, b2, acc2, 0, 0, 0);
    acc3 = __builtin_amdgcn_mfma_f32_16x16x32_f16(af, b3, acc3, 0, 0, 0);
  }
  __syncthreads();  // done reading Xs/Wt; reuse Xs as epilogue buffer
  _Float16* Epi = Xs;  // stride 72
#pragma unroll
  for (int r = 0; r < 4; ++r) {
    int lrow = w * 16 + q * 4 + r;
    int grow = rb + lrow;
    float di = (grow < n) ? dinv[grow] : 0.f;
    Epi[lrow * 72 + lm +  0] = (_Float16)(acc0[r] * di);
    Epi[lrow * 72 + lm + 16] = (_Float16)(acc1[r] * di);
    Epi[lrow * 72 + lm + 32] = (_Float16)(acc2[r] * di);
    Epi[lrow * 72 + lm + 48] = (_Float16)(acc3[r] * di);
  }
  __syncthreads();
  for (int idx = tid; idx < 512; idx += WGS) {  // 64 rows x 8 uint4
    int r = idx >> 3, cg = idx & 7;
    int grow = rb + r;
    if (grow < n)
      *(uint4*)(Y + (long)grow * 64 + cg * 8) = *(const uint4*)&Epi[r * 72 + cg * 8];
  }
}

// ---------- pull aggregation: 8 lanes/node, 8 nodes/wave, 8-deep MLP ----------
#define ACC(raw)                            \
  {                                         \
    a0 = __hadd2(a0, *(__half2*)&(raw).x);  \
    a1 = __hadd2(a1, *(__half2*)&(raw).y);  \
    a2 = __hadd2(a2, *(__half2*)&(raw).z);  \
    a3 = __hadd2(a3, *(__half2*)&(raw).w);  \
  }

template <bool RELU, bool OUTH>
__global__ __launch_bounds__(WGS) void k_aggr(const int2* __restrict__ range,
                                              const int* __restrict__ csr,
                                              const _Float16* __restrict__ g,
                                              const float* __restrict__ dinv,
                                              const float* __restrict__ b,
                                              void* __restrict__ outv, int N) {
  int t = blockIdx.x * WGS + threadIdx.x;
  int node = t >> 3;
  if (node >= N) return;
  int c = threadIdx.x & 7;
  const uint4* gv = (const uint4*)g;
  __half2 a0, a1, a2, a3;
  {  // self loop initializes the accumulator
    uint4 r0 = gv[(long)node * 8 + c];
    a0 = *(__half2*)&r0.x; a1 = *(__half2*)&r0.y;
    a2 = *(__half2*)&r0.z; a3 = *(__half2*)&r0.w;
  }
  int2 rg = range[node];
  const int* cp = csr + rg.x;
  int deg = rg.y - rg.x;
  int i = 0;
  for (; i + 8 <= deg; i += 8) {
    int s0 = cp[i],     s1 = cp[i + 1], s2 = cp[i + 2], s3 = cp[i + 3];
    int s4 = cp[i + 4], s5 = cp[i + 5], s6 = cp[i + 6], s7 = cp[i + 7];
    uint4 r0 = gv[(long)s0 * 8 + c];
    uint4 r1 = gv[(long)s1 * 8 + c];
    uint4 r2 = gv[(long)s2 * 8 + c];
    uint4 r3 = gv[(long)s3 * 8 + c];
    uint4 r4 = gv[(long)s4 * 8 + c];
    uint4 r5 = gv[(long)s5 * 8 + c];
    uint4 r6 = gv[(long)s6 * 8 + c];
    uint4 r7 = gv[(long)s7 * 8 + c];
    ACC(r0); ACC(r1); ACC(r2); ACC(r3);
    ACC(r4); ACC(r5); ACC(r6); ACC(r7);
  }
  if (i + 4 <= deg) {
    int s0 = cp[i], s1 = cp[i + 1], s2 = cp[i + 2], s3 = cp[i + 3];
    uint4 r0 = gv[(long)s0 * 8 + c];
    uint4 r1 = gv[(long)s1 * 8 + c];
    uint4 r2 = gv[(long)s2 * 8 + c];
    uint4 r3 = gv[(long)s3 * 8 + c];
    ACC(r0); ACC(r1); ACC(r2); ACC(r3);
    i += 4;
  }
  for (; i < deg; ++i) {
    uint4 r0 = gv[(long)cp[i] * 8 + c];
    ACC(r0);
  }
  float di = dinv[node];
  float2 f0 = __half22float2(a0), f1 = __half22float2(a1);
  float2 f2 = __half22float2(a2), f3 = __half22float2(a3);
  float4 b0 = ((const float4*)b)[2 * c];
  float4 b1 = ((const float4*)b)[2 * c + 1];
  float o0 = fmaf(f0.x, di, b0.x), o1 = fmaf(f0.y, di, b0.y);
  float o2 = fmaf(f1.x, di, b0.z), o3 = fmaf(f1.y, di, b0.w);
  float o4 = fmaf(f2.x, di, b1.x), o5 = fmaf(f2.y, di, b1.y);
  float o6 = fmaf(f3.x, di, b1.z), o7 = fmaf(f3.y, di, b1.w);
  if (RELU) {
    o0 = fmaxf(o0, 0.f); o1 = fmaxf(o1, 0.f); o2 = fmaxf(o2, 0.f);
    o3 = fmaxf(o3, 0.f); o4 = fmaxf(o4, 0.f); o5 = fmaxf(o5, 0.f);
    o6 = fmaxf(o6, 0.f); o7 = fmaxf(o7, 0.f);
  }
  if (OUTH) {
    __half2 p0 = __floats2half2_rn(o0, o1);
    __half2 p1 = __floats2half2_rn(o2, o3);
    __half2 p2 = __floats2half2_rn(o4, o5);
    __half2 p3 = __floats2half2_rn(o6, o7);
    uint4 pk = make_uint4(*(unsigned*)&p0, *(unsigned*)&p1,
                          *(unsigned*)&p2, *(unsigned*)&p3);
    ((uint4*)outv)[(long)node * 8 + c] = pk;
  } else {
    float* orow = (float*)outv + (long)node * 64 + c * 8;
    *(float4*)orow = make_float4(o0, o1, o2, o3);
    *(float4*)(orow + 4) = make_float4(o4, o5, o6, o7);
  }
}

// ---------- fused layer-1 aggregation + layer-2 GEMM ----------
// REQUIRES N % 32 == 0 (true: 100000 = 3125*32) so no early-outs before barriers.
__global__ __launch_bounds__(WGS) void k_aggr1f(const int2* __restrict__ range,
                                                const int* __restrict__ csr,
                                                const _Float16* __restrict__ g,
                                                const float* __restrict__ dinv,
                                                const float* __restrict__ b,
                                                const _Float16* __restrict__ W2h,
                                                _Float16* __restrict__ g2, int N) {
  __shared__ __align__(16) _Float16 Hs[32 * 72];  // relu(h) tile / epilogue buffer
  const int tid = threadIdx.x;
  const int lnode = tid >> 3;                 // 0..31
  const int node = blockIdx.x * 32 + lnode;   // < N always (grid exact)
  const int c = tid & 7;
  const uint4* gv = (const uint4*)g;
  __half2 a0, a1, a2, a3;
  {  // self loop initializes the accumulator
    uint4 r0 = gv[(long)node * 8 + c];
    a0 = *(__half2*)&r0.x; a1 = *(__half2*)&r0.y;
    a2 = *(__half2*)&r0.z; a3 = *(__half2*)&r0.w;
  }
  int2 rg = range[node];
  const int* cp = csr + rg.x;
  int deg = rg.y - rg.x;
  int i = 0;
  for (; i + 8 <= deg; i += 8) {
    int s0 = cp[i],     s1 = cp[i + 1], s2 = cp[i + 2], s3 = cp[i + 3];
    int s4 = cp[i + 4], s5 = cp[i + 5], s6 = cp[i + 6], s7 = cp[i + 7];
    uint4 r0 = gv[(long)s0 * 8 + c];
    uint4 r1 = gv[(long)s1 * 8 + c];
    uint4 r2 = gv[(long)s2 * 8 + c];
    uint4 r3 = gv[(long)s3 * 8 + c];
    uint4 r4 = gv[(long)s4 * 8 + c];
    uint4 r5 = gv[(long)s5 * 8 + c];
    uint4 r6 = gv[(long)s6 * 8 + c];
    uint4 r7 = gv[(long)s7 * 8 + c];
    ACC(r0); ACC(r1); ACC(r2); ACC(r3);
    ACC(r4); ACC(r5); ACC(r6); ACC(r7);
  }
  if (i + 4 <= deg) {
    int s0 = cp[i], s1 = cp[i + 1], s2 = cp[i + 2], s3 = cp[i + 3];
    uint4 r0 = gv[(long)s0 * 8 + c];
    uint4 r1 = gv[(long)s1 * 8 + c];
    uint4 r2 = gv[(long)s2 * 8 + c];
    uint4 r3 = gv[(long)s3 * 8 + c];
    ACC(r0); ACC(r1); ACC(r2); ACC(r3);
    i += 4;
  }
  for (; i < deg; ++i) {
    uint4 r0 = gv[(long)cp[i] * 8 + c];
    ACC(r0);
  }
  float di = dinv[node];
  float2 f0 = __half22float2(a0), f1 = __half22float2(a1);
  float2 f2 = __half22float2(a2), f3 = __half22float2(a3);
  float4 b0 = ((const float4*)b)[2 * c];
  float4 b1 = ((const float4*)b)[2 * c + 1];
  float o0 = fmaf(f0.x, di, b0.x), o1 = fmaf(f0.y, di, b0.y);
  float o2 = fmaf(f1.x, di, b0.z), o3 = fmaf(f1.y, di, b0.w);
  float o4 = fmaf(f2.x, di, b1.x), o5 = fmaf(f2.y, di, b1.y);
  float o6 = fmaf(f3.x, di, b1.z), o7 = fmaf(f3.y, di, b1.w);
  o0 = fmaxf(o0, 0.f); o1 = fmaxf(o1, 0.f); o2 = fmaxf(o2, 0.f);
  o3 = fmaxf(o3, 0.f); o4 = fmaxf(o4, 0.f); o5 = fmaxf(o5, 0.f);
  o6 = fmaxf(o6, 0.f); o7 = fmaxf(o7, 0.f);
  {  // h tile (same __floats2half2_rn rounding) -> LDS, stride 72
    __half2 p0 = __floats2half2_rn(o0, o1);
    __half2 p1 = __floats2half2_rn(o2, o3);
    __half2 p2 = __floats2half2_rn(o4, o5);
    __half2 p3 = __floats2half2_rn(o6, o7);
    uint4 pk = make_uint4(*(unsigned*)&p0, *(unsigned*)&p1,
                          *(unsigned*)&p2, *(unsigned*)&p3);
    *(uint4*)&Hs[lnode * 72 + c * 8] = pk;
  }
  __syncthreads();
  // 32x64 = relu(H) @ W2: 4 waves; wave w -> m-tile (w&1), n-tiles {2*(w>>1), +1}
  const int w = tid >> 6, l = tid & 63;
  const int lm = l & 15, q = l >> 4;
  const int mt = w & 1, n0 = (w >> 1) << 1;
  const _Float16* ab = &Hs[(mt * 16 + lm) * 72 + q * 8];
  const _Float16* wb = W2h + (n0 * 16 + lm) * 72 + q * 8;  // B-frags from L2
  f32x4_t acc0 = {0.f, 0.f, 0.f, 0.f}, acc1 = acc0;
#pragma unroll
  for (int ks = 0; ks < 2; ++ks) {
    half8_t af = *(const half8_t*)(ab + ks * 32);
    half8_t w0 = *(const half8_t*)(wb + ks * 32);
    half8_t w1 = *(const half8_t*)(wb + 16 * 72 + ks * 32);
    acc0 = __builtin_amdgcn_mfma_f32_16x16x32_f16(af, w0, acc0, 0, 0, 0);
    acc1 = __builtin_amdgcn_mfma_f32_16x16x32_f16(af, w1, acc1, 0, 0, 0);
  }
  __syncthreads();  // all waves done reading Hs; reuse as epilogue buffer
#pragma unroll
  for (int r = 0; r < 4; ++r) {
    int lrow = mt * 16 + q * 4 + r;
    float d2 = dinv[blockIdx.x * 32 + lrow];
    Hs[lrow * 72 + n0 * 16 + lm]       = (_Float16)(acc0[r] * d2);
    Hs[lrow * 72 + (n0 + 1) * 16 + lm] = (_Float16)(acc1[r] * d2);
  }
  __syncthreads();
  {  // coalesced store: 32 rows x 8 uint4
    int rr = tid >> 3, cg = tid & 7;
    *(uint4*)(g2 + (long)(blockIdx.x * 32 + rr) * 64 + cg * 8) =
        *(const uint4*)&Hs[rr * 72 + cg * 8];
  }
}
#undef ACC

extern "C" void kernel_launch(void* const* d_in, const int* in_sizes, int n_in,
                              void* d_out, int out_size, void* d_ws, size_t ws_size,
                              hipStream_t stream) {
  const float* x  = (const float*)d_in[0];
  const int*   ei = (const int*)d_in[1];
  const float* W1 = (const float*)d_in[2];
  const float* b1 = (const float*)d_in[3];
  const float* W2 = (const float*)d_in[4];
  const float* b2 = (const float*)d_in[5];
  float* out = (float*)d_out;

  const int N = in_sizes[0] / 128;  // 100000
  const int E = in_sizes[1] / 2;    // 1600000
  const int* row = ei;              // sources
  const int* col = ei + E;          // targets

  const int nbk = (N + (1 << BSH) - 1) >> BSH;  // 782 buckets (<=1024)
  const int PB  = (E + TILE - 1) / TILE;        // partition blocks (196)

  int Npad = (N + 3) & ~3;
  int*      bcur  = (int*)d_ws;              // [1024]  (zeroed)
  float*    dinv  = (float*)(bcur + 1024);   // [Npad]
  int2*     range = (int2*)(dinv + Npad);    // [N]
  int*      csr   = (int*)(range + N);       // [nbk*CAP]
  int*      ebuf  = csr + (size_t)nbk * CAP; // [nbk*CAP]
  _Float16* g     = (_Float16*)(ebuf + (size_t)nbk * CAP);  // [N*64] fp16
  _Float16* g2    = g + (size_t)N * 64;      // [N*64] fp16 (layer-2 pre-agg)
  _Float16* W2h   = g2 + (size_t)N * 64;     // [64*72] fp16 transposed W2

  // ---- CSR build + normalization (LDS counting sort); +1 block converts W2 ----
  hipMemsetAsync(bcur, 0, 1024 * sizeof(int), stream);
  k_partA<<<PB + 1, HWGS, 0, stream>>>(row, col, bcur, ebuf, W2, W2h, E, nbk, PB);
  k_partB<<<nbk, WGS, 0, stream>>>(ebuf, bcur, range, dinv, csr, N);

  // ---- layer 1 GEMM ----
  k_gemm<128, false><<<(N + 63) / 64, WGS, 0, stream>>>(x, W1, dinv, g, N);

  // ---- layer-1 aggregation fused with layer-2 GEMM ----
  k_aggr1f<<<(N + 31) / 32, WGS, 0, stream>>>(range, csr, g, dinv, b1, W2h, g2, N);

  // ---- layer-2 aggregation ----
  int aggGrid = (N * 8 + WGS - 1) / WGS;  // 8 lanes per node
  k_aggr<false, false><<<aggGrid, WGS, 0, stream>>>(range, csr, g2, dinv, b2, out, N);
}